// Round 16
// baseline (98.235 us; speedup 1.0000x reference)
//
#include <hip/hip_runtime.h>
#include <hip/hip_bf16.h>

// TopicRouter: logits = h @ gate_w^T + gate_b ; top-2 ; softmax over top-2.
// Outputs flat in d_out (float32): [0, 2B)   = topk idx as floats
//                                  [2B, 4B)  = softmax weights
//
// R16 = R15 (MFMA hi/lo 3-product, two tiles/wave; 86.3 us) FUSED:
//  * repair inlined as a wave-uniform rare branch (ballot-built 32-bit mask
//    over the wave's 32 tokens) -> second launch, flags buffer, and 512-block
//    scan all removed. Ambiguous tokens are stored ONLY by the repair path
//    (hot path skips them) -> each token stored exactly once, no ordering
//    hazard. Cold path is register-lean: gw re-read from L2 per use (no
//    96-reg cache), everything branch-local.
//  * R14/R15 nulls: latency depth and line-coalescing both falsified; VALU/
//    DS/MFMA arithmetic all << 86 us. Residual gap over the 64 us stream
//    floor attributed to (a) launch/flag overhead [this round] and (b) the
//    stride-3KB 16-row DRAM pattern [structural: MFMA k-slice fragments vs
//    48KB/tile sequential staging that LDS can't hold].
//  * Math unchanged: mfma_f32_16x16x32_bf16, hi*hi+hi*lo+lo*hi (dropped
//    lo*lo ~2e-5 << TAU=2.5e-4); f64 repair guarantees exact top-2 ranking
//    (one rank flip vs the f64 np ref fails the 0.14 idx threshold).
//  * C layout (m89-verified): col = lane&15, row = (lane>>4)*4 + reg.

#define B_TOKENS 131072
#define DM 768
#define NE 8
#define TAU 2.5e-4f
#define NEG_BIG -3.0e38f

typedef __attribute__((ext_vector_type(8))) short bf16x8;
typedef __attribute__((ext_vector_type(4))) float f32x4;

__device__ __forceinline__ unsigned short f32_to_bf16(float f) {
    __hip_bfloat16 b = __float2bfloat16(f);
    return *reinterpret_cast<unsigned short*>(&b);
}
__device__ __forceinline__ float bf16_to_f32(unsigned short u) {
    return __uint_as_float((unsigned)u << 16);
}

__global__ __launch_bounds__(256) void router_fused(
    const float* __restrict__ h,     // [B, 768]
    const float* __restrict__ gw,    // [8, 768]
    const float* __restrict__ gb,    // [8]
    float* __restrict__ out)         // [2B idx floats][2B weight floats]
{
    // [kstep 24][col 8: 72 ushorts = 32 hi + 32 lo + 8 pad] + 8 zero stub
    __shared__ __align__(16) unsigned short w_lds[24 * 576 + 8];

    const int tid  = threadIdx.x;
    const int lane = tid & 63;
    const int wv   = tid >> 6;
    const int col  = lane & 15;
    const int kg   = lane >> 4;

    // ---- build B hi/lo in LDS, k-permuted to match coalesced A loads ----
    for (int idx = tid; idx < NE * DM; idx += 256) {
        const int e = idx / DM, k = idx - e * DM;
        const float w = gw[idx];
        const unsigned short hb = f32_to_bf16(w);
        const unsigned short lb = f32_to_bf16(w - bf16_to_f32(hb));
        const int ks = k >> 5, kk = k & 31;
        const int phys = (((kk & 15) >> 2) << 3) + (kk & 3) + ((kk & 16) ? 4 : 0);
        w_lds[ks * 576 + e * 72 + phys]      = hb;
        w_lds[ks * 576 + e * 72 + 32 + phys] = lb;
    }
    if (tid < 8) w_lds[24 * 576 + tid] = 0;

    const float bias_lane = (col < 8) ? gb[col] : NEG_BIG;
    __syncthreads();

    // ---- per-wave: two adjacent 16-token tiles ----
    const int tile0 = (blockIdx.x * 4 + wv) * 2;     // [0, 8192) step 2
    const float* arow0 = h + (size_t)(tile0 * 16 + col) * DM + kg * 4;
    const float* arow1 = arow0 + (size_t)16 * DM;

    const unsigned short* bptr =
        (col < 8) ? &w_lds[col * 72 + kg * 8] : &w_lds[24 * 576];
    const int bstep = (col < 8) ? 576 : 0;
    const int bloff = (col < 8) ? 32 : 0;

    f32x4 acc0 = {0.f, 0.f, 0.f, 0.f};
    f32x4 acc1 = {0.f, 0.f, 0.f, 0.f};

#pragma unroll 2
    for (int ks = 0; ks < 24; ++ks) {
        const float4 p0 = *reinterpret_cast<const float4*>(arow0 + ks * 32);
        const float4 q0 = *reinterpret_cast<const float4*>(arow0 + ks * 32 + 16);
        const float4 p1 = *reinterpret_cast<const float4*>(arow1 + ks * 32);
        const float4 q1 = *reinterpret_cast<const float4*>(arow1 + ks * 32 + 16);

        const bf16x8 bhi = *reinterpret_cast<const bf16x8*>(bptr + ks * bstep);
        const bf16x8 blo = *reinterpret_cast<const bf16x8*>(bptr + ks * bstep + bloff);

        bf16x8 ahi0, alo0, ahi1, alo1;
        {
            const float f0[8] = {p0.x, p0.y, p0.z, p0.w, q0.x, q0.y, q0.z, q0.w};
            const float f1[8] = {p1.x, p1.y, p1.z, p1.w, q1.x, q1.y, q1.z, q1.w};
#pragma unroll
            for (int j = 0; j < 8; ++j) {
                unsigned short hb = f32_to_bf16(f0[j]);
                ahi0[j] = (short)hb;
                alo0[j] = (short)f32_to_bf16(f0[j] - bf16_to_f32(hb));
                hb = f32_to_bf16(f1[j]);
                ahi1[j] = (short)hb;
                alo1[j] = (short)f32_to_bf16(f1[j] - bf16_to_f32(hb));
            }
        }
        acc0 = __builtin_amdgcn_mfma_f32_16x16x32_bf16(ahi0, bhi, acc0, 0, 0, 0);
        acc0 = __builtin_amdgcn_mfma_f32_16x16x32_bf16(ahi0, blo, acc0, 0, 0, 0);
        acc0 = __builtin_amdgcn_mfma_f32_16x16x32_bf16(alo0, bhi, acc0, 0, 0, 0);
        acc1 = __builtin_amdgcn_mfma_f32_16x16x32_bf16(ahi1, bhi, acc1, 0, 0, 0);
        acc1 = __builtin_amdgcn_mfma_f32_16x16x32_bf16(ahi1, blo, acc1, 0, 0, 0);
        acc1 = __builtin_amdgcn_mfma_f32_16x16x32_bf16(alo1, bhi, acc1, 0, 0, 0);
    }

    // ---- epilogue: store unambiguous tokens; collect ambiguous in a mask ----
    const unsigned gsh = (unsigned)(lane & 48);
    unsigned wavemask = 0;   // bit (tsel*16 + kg*4 + i) = token needs repair

    auto epi = [&](const f32x4& acc, int tile, int tsel) {
#pragma unroll
        for (int i = 0; i < 4; ++i) {
            const float lg = acc[i] + bias_lane;    // cols>=8: 0 + (-3e38)
            float a0 = lg, a1 = NEG_BIG, a2 = NEG_BIG;
#pragma unroll
            for (int m = 1; m <= 4; m <<= 1) {
                const float b0 = __shfl_xor(a0, m);
                const float b1 = __shfl_xor(a1, m);
                const float b2 = __shfl_xor(a2, m);
                const float x  = fminf(a0, b0);
                const float c0 = fmaxf(a0, b0);
                const float y  = fmaxf(a1, b1);
                const float z  = fminf(a1, b1);
                const float c1 = fmaxf(x, y);
                const float c2 = fmaxf(fminf(x, y), fmaxf(z, fmaxf(a2, b2)));
                a0 = c0; a1 = c1; a2 = c2;
            }
            const unsigned long long m0 = __ballot(lg == a0);
            const unsigned long long m1 = __ballot(lg == a1);
            const unsigned mk0 = (unsigned)(m0 >> gsh) & 0xFFu;
            const unsigned mk1 = (unsigned)(m1 >> gsh) & 0xFFu;
            const int i0 = __builtin_ctz(mk0);
            const unsigned rest = mk0 & (mk0 - 1);
            const int i1 = (a1 == a0) ? __builtin_ctz(rest | 0x100u)
                                      : __builtin_ctz(mk1 | 0x100u);

            const bool amb = (a0 - a1 < TAU) || (a1 - a2 < TAU);

            // collect ambiguity wave-uniformly (ballot is uniform)
            const unsigned long long ab = __ballot((col == 0) && amb);
            const unsigned base = (unsigned)(tsel * 16 + i);
            wavemask |= ((unsigned)(ab >> 0)  & 1u) << (base + 0);
            wavemask |= ((unsigned)(ab >> 16) & 1u) << (base + 4);
            wavemask |= ((unsigned)(ab >> 32) & 1u) << (base + 8);
            wavemask |= ((unsigned)(ab >> 48) & 1u) << (base + 12);

            const float ex = expf(a1 - a0);        // <= 1
            const float w1 = ex / (1.f + ex);
            const float w0 = 1.f - w1;

            if (col == 0 && !amb) {
                const size_t t = (size_t)(tile * 16 + (lane >> 4) * 4 + i);
                *reinterpret_cast<float2*>(&out[2 * t]) =
                    make_float2((float)i0, (float)i1);
                *reinterpret_cast<float2*>(&out[2 * (size_t)B_TOKENS + 2 * t]) =
                    make_float2(w0, w1);
            }
        }
    };
    epi(acc0, tile0, 0);
    epi(acc1, tile0 + 1, 1);

    // ---- cold, rare: exact f64 repair for ambiguous tokens (~2e-3 rate) ----
    if (__builtin_expect(wavemask != 0, 0)) {
        const bool hi32 = (lane & 32) != 0;
        const bool hi16 = (lane & 16) != 0;
        const bool hi8  = (lane & 8)  != 0;
        while (wavemask) {
            const int p = __builtin_ctz(wavemask);
            wavemask &= wavemask - 1;
            const int t = tile0 * 16 + p;

            const float* hr = h + (size_t)t * DM;
            float4 buf[3];
#pragma unroll
            for (int g = 0; g < 3; ++g)
                buf[g] = *reinterpret_cast<const float4*>(&hr[g * 256 + lane * 4]);

            double acc[NE] = {0, 0, 0, 0, 0, 0, 0, 0};
#pragma unroll
            for (int g = 0; g < 3; ++g) {
                const float* bp = reinterpret_cast<const float*>(&buf[g]);
#pragma unroll
                for (int e = 0; e < NE; ++e) {
                    const float4 wv4 = *reinterpret_cast<const float4*>(
                        &gw[e * DM + g * 256 + lane * 4]);
                    acc[e] = fma((double)bp[0], (double)wv4.x, acc[e]);
                    acc[e] = fma((double)bp[1], (double)wv4.y, acc[e]);
                    acc[e] = fma((double)bp[2], (double)wv4.z, acc[e]);
                    acc[e] = fma((double)bp[3], (double)wv4.w, acc[e]);
                }
            }
            double d4[4];
#pragma unroll
            for (int j = 0; j < 4; ++j) {
                const double give = hi32 ? acc[j] : acc[4 + j];
                const double keep = hi32 ? acc[4 + j] : acc[j];
                d4[j] = keep + __shfl_xor(give, 32);
            }
            double d2[2];
#pragma unroll
            for (int j = 0; j < 2; ++j) {
                const double give = hi16 ? d4[j] : d4[2 + j];
                const double keep = hi16 ? d4[2 + j] : d4[j];
                d2[j] = keep + __shfl_xor(give, 16);
            }
            const double give = hi8 ? d2[0] : d2[1];
            const double keep = hi8 ? d2[1] : d2[0];
            double dv = keep + __shfl_xor(give, 8);
            dv += __shfl_xor(dv, 4);
            dv += __shfl_xor(dv, 2);
            dv += __shfl_xor(dv, 1);

            double dlg[NE];
#pragma unroll
            for (int e = 0; e < NE; ++e)
                dlg[e] = __shfl(dv, (e << 3) | (lane & 7)) + (double)gb[e];

            int i0 = 0; double dv0 = dlg[0];
#pragma unroll
            for (int e = 1; e < NE; ++e)
                if (dlg[e] > dv0) { dv0 = dlg[e]; i0 = e; }
            int i1 = (i0 == 0) ? 1 : 0; double dv1 = dlg[i1];
#pragma unroll
            for (int e = 0; e < NE; ++e)
                if (e != i0 && dlg[e] > dv1) { dv1 = dlg[e]; i1 = e; }

            const float ex = expf((float)(dv1 - dv0));
            const float w1 = ex / (1.0f + ex);
            const float w0 = 1.0f - w1;

            if (lane == 0) {
                *reinterpret_cast<float2*>(&out[2 * (size_t)t]) =
                    make_float2((float)i0, (float)i1);
                *reinterpret_cast<float2*>(
                    &out[2 * (size_t)B_TOKENS + 2 * (size_t)t]) =
                    make_float2(w0, w1);
            }
        }
    }
}

extern "C" void kernel_launch(void* const* d_in, const int* in_sizes, int n_in,
                              void* d_out, int out_size, void* d_ws, size_t ws_size,
                              hipStream_t stream) {
    const float* h  = (const float*)d_in[0];
    const float* gw = (const float*)d_in[1];
    const float* gb = (const float*)d_in[2];
    float* out = (float*)d_out;

    router_fused<<<dim3(1024), dim3(256), 0, stream>>>(h, gw, gb, out);
}

// Round 17
// 86.601 us; speedup vs baseline: 1.1343x; 1.1343x over previous
//
#include <hip/hip_runtime.h>
#include <hip/hip_bf16.h>

// TopicRouter: logits = h @ gate_w^T + gate_b ; top-2 ; softmax over top-2.
// Outputs flat in d_out (float32): [0, 2B)   = topk idx as floats
//                                  [2B, 4B)  = softmax weights
//
// R17 = R15 (best: 86.3 us; MFMA hi/lo 3-product, two tiles/wave, k-permuted
// coalesced loads, two-kernel f64 repair) + UNROLL 2->4 in the k-loop.
//  * R16 (inline repair fusion) regressed 86->98: cold-path f64 VGPRs + 8
//    extra ballots/epilogue cost more than the ~5us second launch. Reverted.
//  * Residual theory: DRAM page locality. A wave interleaves 32 row-streams
//    (3KB stride), 128B per visit -> page thrash. Unroll 4 issues 256B
//    sequential per row per visit (4x 64B pieces back-to-back). If null,
//    ~86us = 74% of contiguous-copy BW + 2 launches is this op's floor.
//  * Math unchanged: mfma_f32_16x16x32_bf16, hi*hi+hi*lo+lo*hi (dropped
//    lo*lo ~2e-5 << TAU=2.5e-4); flag + f64 repair kernel guarantees exact
//    top-2 ranking (one rank flip vs f64 np ref fails the 0.14 threshold).
//  * C layout (m89-verified): col = lane&15, row = (lane>>4)*4 + reg.

#define B_TOKENS 131072
#define DM 768
#define NE 8
#define TAU 2.5e-4f
#define NEG_BIG -3.0e38f

typedef __attribute__((ext_vector_type(8))) short bf16x8;
typedef __attribute__((ext_vector_type(4))) float f32x4;

__device__ __forceinline__ unsigned short f32_to_bf16(float f) {
    __hip_bfloat16 b = __float2bfloat16(f);
    return *reinterpret_cast<unsigned short*>(&b);
}
__device__ __forceinline__ float bf16_to_f32(unsigned short u) {
    return __uint_as_float((unsigned)u << 16);
}

__global__ __launch_bounds__(256) void router_main(
    const float* __restrict__ h,     // [B, 768]
    const float* __restrict__ gw,    // [8, 768]
    const float* __restrict__ gb,    // [8]
    float* __restrict__ out,         // [2B idx floats][2B weight floats]
    unsigned char* __restrict__ flags)
{
    // [kstep 24][col 8: 72 ushorts = 32 hi + 32 lo + 8 pad] + 8 zero stub
    __shared__ __align__(16) unsigned short w_lds[24 * 576 + 8];

    const int tid  = threadIdx.x;
    const int lane = tid & 63;
    const int wv   = tid >> 6;
    const int col  = lane & 15;
    const int kg   = lane >> 4;

    // ---- build B hi/lo in LDS, k-permuted to match coalesced A loads ----
    for (int idx = tid; idx < NE * DM; idx += 256) {
        const int e = idx / DM, k = idx - e * DM;
        const float w = gw[idx];
        const unsigned short hb = f32_to_bf16(w);
        const unsigned short lb = f32_to_bf16(w - bf16_to_f32(hb));
        const int ks = k >> 5, kk = k & 31;
        const int phys = (((kk & 15) >> 2) << 3) + (kk & 3) + ((kk & 16) ? 4 : 0);
        w_lds[ks * 576 + e * 72 + phys]      = hb;
        w_lds[ks * 576 + e * 72 + 32 + phys] = lb;
    }
    if (tid < 8) w_lds[24 * 576 + tid] = 0;

    const float bias_lane = (col < 8) ? gb[col] : NEG_BIG;
    __syncthreads();

    // ---- per-wave: two adjacent 16-token tiles ----
    const int tile0 = (blockIdx.x * 4 + wv) * 2;     // [0, 8192) step 2
    const float* arow0 = h + (size_t)(tile0 * 16 + col) * DM + kg * 4;
    const float* arow1 = arow0 + (size_t)16 * DM;

    const unsigned short* bptr =
        (col < 8) ? &w_lds[col * 72 + kg * 8] : &w_lds[24 * 576];
    const int bstep = (col < 8) ? 576 : 0;
    const int bloff = (col < 8) ? 32 : 0;

    f32x4 acc0 = {0.f, 0.f, 0.f, 0.f};
    f32x4 acc1 = {0.f, 0.f, 0.f, 0.f};

#pragma unroll 4
    for (int ks = 0; ks < 24; ++ks) {
        // fully-coalesced: p at +0 (kg*16B within 64B), q at +64B
        const float4 p0 = *reinterpret_cast<const float4*>(arow0 + ks * 32);
        const float4 q0 = *reinterpret_cast<const float4*>(arow0 + ks * 32 + 16);
        const float4 p1 = *reinterpret_cast<const float4*>(arow1 + ks * 32);
        const float4 q1 = *reinterpret_cast<const float4*>(arow1 + ks * 32 + 16);

        const bf16x8 bhi = *reinterpret_cast<const bf16x8*>(bptr + ks * bstep);
        const bf16x8 blo = *reinterpret_cast<const bf16x8*>(bptr + ks * bstep + bloff);

        bf16x8 ahi0, alo0, ahi1, alo1;
        {
            const float f0[8] = {p0.x, p0.y, p0.z, p0.w, q0.x, q0.y, q0.z, q0.w};
            const float f1[8] = {p1.x, p1.y, p1.z, p1.w, q1.x, q1.y, q1.z, q1.w};
#pragma unroll
            for (int j = 0; j < 8; ++j) {
                unsigned short hb = f32_to_bf16(f0[j]);
                ahi0[j] = (short)hb;
                alo0[j] = (short)f32_to_bf16(f0[j] - bf16_to_f32(hb));
                hb = f32_to_bf16(f1[j]);
                ahi1[j] = (short)hb;
                alo1[j] = (short)f32_to_bf16(f1[j] - bf16_to_f32(hb));
            }
        }
        acc0 = __builtin_amdgcn_mfma_f32_16x16x32_bf16(ahi0, bhi, acc0, 0, 0, 0);
        acc0 = __builtin_amdgcn_mfma_f32_16x16x32_bf16(ahi0, blo, acc0, 0, 0, 0);
        acc0 = __builtin_amdgcn_mfma_f32_16x16x32_bf16(alo0, bhi, acc0, 0, 0, 0);
        acc1 = __builtin_amdgcn_mfma_f32_16x16x32_bf16(ahi1, bhi, acc1, 0, 0, 0);
        acc1 = __builtin_amdgcn_mfma_f32_16x16x32_bf16(ahi1, blo, acc1, 0, 0, 0);
        acc1 = __builtin_amdgcn_mfma_f32_16x16x32_bf16(alo1, bhi, acc1, 0, 0, 0);
    }

    // ---- epilogue per tile: top-3 merge butterfly + ballot argmax ----
    const unsigned gsh = (unsigned)(lane & 48);

    auto epi = [&](const f32x4& acc, int tile) {
#pragma unroll
        for (int i = 0; i < 4; ++i) {
            const float lg = acc[i] + bias_lane;    // cols>=8: 0 + (-3e38)
            float a0 = lg, a1 = NEG_BIG, a2 = NEG_BIG;
#pragma unroll
            for (int m = 1; m <= 4; m <<= 1) {
                const float b0 = __shfl_xor(a0, m);
                const float b1 = __shfl_xor(a1, m);
                const float b2 = __shfl_xor(a2, m);
                const float x  = fminf(a0, b0);
                const float c0 = fmaxf(a0, b0);
                const float y  = fmaxf(a1, b1);
                const float z  = fminf(a1, b1);
                const float c1 = fmaxf(x, y);
                const float c2 = fmaxf(fminf(x, y), fmaxf(z, fmaxf(a2, b2)));
                a0 = c0; a1 = c1; a2 = c2;
            }
            // argmax via ballot; exact lax.top_k tie-break (lower index wins)
            const unsigned long long m0 = __ballot(lg == a0);
            const unsigned long long m1 = __ballot(lg == a1);
            const unsigned mk0 = (unsigned)(m0 >> gsh) & 0xFFu;
            const unsigned mk1 = (unsigned)(m1 >> gsh) & 0xFFu;
            const int i0 = __builtin_ctz(mk0);
            const unsigned rest = mk0 & (mk0 - 1);
            const int i1 = (a1 == a0) ? __builtin_ctz(rest | 0x100u)
                                      : __builtin_ctz(mk1 | 0x100u);

            const bool amb = (a0 - a1 < TAU) || (a1 - a2 < TAU);
            const float ex = expf(a1 - a0);        // <= 1
            const float w1 = ex / (1.f + ex);
            const float w0 = 1.f - w1;

            if (col == 0) {
                const size_t t = (size_t)(tile * 16 + (lane >> 4) * 4 + i);
                *reinterpret_cast<float2*>(&out[2 * t]) =
                    make_float2((float)i0, (float)i1);
                *reinterpret_cast<float2*>(&out[2 * (size_t)B_TOKENS + 2 * t]) =
                    make_float2(w0, w1);
                flags[t] = amb ? 1 : 0;            // always written
            }
        }
    };
    epi(acc0, tile0);
    epi(acc1, tile0 + 1);
}

// One wave per 64 consecutive tokens; early-exit when no flags set. (R9-proven.)
__global__ __launch_bounds__(256) void router_repair(
    const float* __restrict__ h,
    const float* __restrict__ gw,
    const float* __restrict__ gb,
    float* __restrict__ out,
    const unsigned char* __restrict__ flags)
{
    const int lane = threadIdx.x & 63;
    const int w = (blockIdx.x * blockDim.x + threadIdx.x) >> 6;
    const int t0 = w * 64;
    if (t0 >= B_TOKENS) return;

    const unsigned char f = flags[t0 + lane];
    unsigned long long mask = __ballot(f != 0);
    if (mask == 0ull) return;

    float wf[NE][3][4];
#pragma unroll
    for (int e = 0; e < NE; ++e)
#pragma unroll
        for (int g = 0; g < 3; ++g) {
            const float4 vv = *reinterpret_cast<const float4*>(
                &gw[e * DM + g * 256 + lane * 4]);
            wf[e][g][0] = vv.x; wf[e][g][1] = vv.y;
            wf[e][g][2] = vv.z; wf[e][g][3] = vv.w;
        }
    double biasd[NE];
#pragma unroll
    for (int e = 0; e < NE; ++e) biasd[e] = (double)gb[e];

    const bool hi32 = (lane & 32) != 0;
    const bool hi16 = (lane & 16) != 0;
    const bool hi8  = (lane & 8)  != 0;

    while (mask) {
        const int p = __ffsll((unsigned long long)mask) - 1;
        mask &= (mask - 1);
        const int t = t0 + p;

        const float* hr = h + (size_t)t * DM;
        float4 buf[3];
#pragma unroll
        for (int g = 0; g < 3; ++g)
            buf[g] = *reinterpret_cast<const float4*>(&hr[g * 256 + lane * 4]);

        double acc[NE] = {0, 0, 0, 0, 0, 0, 0, 0};
#pragma unroll
        for (int g = 0; g < 3; ++g) {
            const float* bp = reinterpret_cast<const float*>(&buf[g]);
#pragma unroll
            for (int j = 0; j < 4; ++j) {
                const double hd = (double)bp[j];
#pragma unroll
                for (int e = 0; e < NE; ++e)
                    acc[e] = fma(hd, (double)wf[e][g][j], acc[e]);
            }
        }
        double d4[4];
#pragma unroll
        for (int j = 0; j < 4; ++j) {
            const double give = hi32 ? acc[j] : acc[4 + j];
            const double keep = hi32 ? acc[4 + j] : acc[j];
            d4[j] = keep + __shfl_xor(give, 32);
        }
        double d2[2];
#pragma unroll
        for (int j = 0; j < 2; ++j) {
            const double give = hi16 ? d4[j] : d4[2 + j];
            const double keep = hi16 ? d4[2 + j] : d4[j];
            d2[j] = keep + __shfl_xor(give, 16);
        }
        const double give = hi8 ? d2[0] : d2[1];
        const double keep = hi8 ? d2[1] : d2[0];
        double dv = keep + __shfl_xor(give, 8);
        dv += __shfl_xor(dv, 4);
        dv += __shfl_xor(dv, 2);
        dv += __shfl_xor(dv, 1);

        double dlg[NE];
#pragma unroll
        for (int e = 0; e < NE; ++e)
            dlg[e] = __shfl(dv, (e << 3) | (lane & 7)) + biasd[e];

        int i0 = 0; double dv0 = dlg[0];
#pragma unroll
        for (int e = 1; e < NE; ++e)
            if (dlg[e] > dv0) { dv0 = dlg[e]; i0 = e; }
        int i1 = (i0 == 0) ? 1 : 0; double dv1 = dlg[i1];
#pragma unroll
        for (int e = 0; e < NE; ++e)
            if (e != i0 && dlg[e] > dv1) { dv1 = dlg[e]; i1 = e; }

        const float ex = expf((float)(dv1 - dv0));
        const float w1 = ex / (1.0f + ex);
        const float w0 = 1.0f - w1;

        if (lane == 0) {
            *reinterpret_cast<float2*>(&out[2 * (size_t)t]) =
                make_float2((float)i0, (float)i1);
            *reinterpret_cast<float2*>(
                &out[2 * (size_t)B_TOKENS + 2 * (size_t)t]) =
                make_float2(w0, w1);
        }
    }
}

extern "C" void kernel_launch(void* const* d_in, const int* in_sizes, int n_in,
                              void* d_out, int out_size, void* d_ws, size_t ws_size,
                              hipStream_t stream) {
    const float* h  = (const float*)d_in[0];
    const float* gw = (const float*)d_in[1];
    const float* gb = (const float*)d_in[2];
    float* out = (float*)d_out;
    unsigned char* flags = (unsigned char*)d_ws;   // B_TOKENS bytes

    router_main<<<dim3(1024), dim3(256), 0, stream>>>(h, gw, gb, out, flags);
    router_repair<<<dim3(512), dim3(256), 0, stream>>>(h, gw, gb, out, flags);
}